// Round 5
// baseline (186.472 us; speedup 1.0000x reference)
//
#include <hip/hip_runtime.h>

static constexpr int OHW = 12, NSP = 144;

// ---------------------------------------------------------------------------
// build_T: gather x (4,256,14,14) -> T[n][k][i], n = b*144+oh*12+ow,
// k = (kh*3+kw)*32 + ic, i in [0,8). One float4 (4 consecutive i) per thread.
// (~4 us; fusing it into caps_main was tried and regressed phase 1 by 11 us.)
// ---------------------------------------------------------------------------
__global__ void build_T(const float* __restrict__ x, float4* __restrict__ T4) {
    const int g = blockIdx.x * 256 + threadIdx.x;   // [0, 576*576)
    const int n = g / 576;                          // 576 float4 per n
    const int q = g - n * 576;
    const int r = q << 2;                           // float offset in row
    const int k = r >> 3;
    const int i0 = r & 7;                           // 0 or 4
    const int ic = k & 31;
    const int kk = k >> 5;
    const int kh = kk / 3, kw = kk - kh * 3;
    const int b = n / NSP;
    const int rm = n - b * NSP;
    const int oh = rm / OHW, ow = rm - oh * OHW;
    const float* xp = x + (size_t)(b * 256 + ic * 8 + i0) * 196
                        + (oh + kh) * 14 + (ow + kw);
    float4 v;
    v.x = xp[0];
    v.y = xp[196];
    v.z = xp[392];
    v.w = xp[588];
    T4[g] = v;
}

__device__ __forceinline__ void fma4(float4& a, float s, const float4& w) {
    a.x = fmaf(s, w.x, a.x);
    a.y = fmaf(s, w.y, a.y);
    a.z = fmaf(s, w.z, a.z);
    a.w = fmaf(s, w.w, a.w);
}

__device__ __forceinline__ void add4(float4& a, const float4& b) {
    a.x += b.x; a.y += b.y; a.z += b.z; a.w += b.w;
}

__device__ __forceinline__ float4 shfl_xor4(const float4& v, int m) {
    float4 r;
    r.x = __shfl_xor(v.x, m);
    r.y = __shfl_xor(v.y, m);
    r.z = __shfl_xor(v.z, m);
    r.w = __shfl_xor(v.w, m);
    return r;
}

// Compute one k-slab (16 k x 4 c x 4 n): load w[8] once, produce 4 n's prior
// quads, write LDS. k = (lane>>2) + 16*g. LDS write address = const + lane
// (lane-consecutive, conflict-free b128).
__device__ __forceinline__ void do_j(const float4* __restrict__ T4,
                                     const float4* __restrict__ W4,
                                     float4* __restrict__ Pl,
                                     int o, int nbase, int k, int cg,
                                     int g_local, int lane) {
    float4 w[8];
    const float4* wp = W4 + (size_t)(o * 288 + k) * 32 + cg;
    #pragma unroll
    for (int i = 0; i < 8; ++i) w[i] = wp[i * 4];
    #pragma unroll
    for (int nn = 0; nn < 4; ++nn) {
        const float4* tp = T4 + (size_t)(nbase + nn) * 576 + k * 2;
        const float4 t0 = tp[0];
        const float4 t1 = tp[1];
        float4 a = make_float4(0.f, 0.f, 0.f, 0.f);
        fma4(a, t0.x, w[0]); fma4(a, t0.y, w[1]);
        fma4(a, t0.z, w[2]); fma4(a, t0.w, w[3]);
        fma4(a, t1.x, w[4]); fma4(a, t1.y, w[5]);
        fma4(a, t1.z, w[6]); fma4(a, t1.w, w[7]);
        Pl[nn * 576 + g_local * 64 + lane] = a;
    }
}

// ---------------------------------------------------------------------------
// caps_main: block = (o, 4 n's), 512 threads = 8 waves. Wave = (n_local,
// k_half); per-lane routing state P[9] f4 = 36 regs. Round-4 lesson:
// __launch_bounds__ second arg maps to a ~240/arg register budget on this
// toolchain ((256,6) and (512,6) both produced 40 VGPR + 73 MB scratch).
// (512,3) -> ~80-reg budget, above the ~70-reg natural peak (do_j ~55;
// phase2 P[9]+lj[9]+temps ~60), so no spill; occupancy then lands where R4
// measured the structure: ~57%.
// Phase 1: chunk0 = slabs 0-8 by all 8 waves, khalf0 waves read their P;
// chunk1 = slabs 9-17 by khalf1 waves only, so khalf0 never holds P[9]
// concurrently with do_j's live set.
// Phase 2: intra-wave kgp-reduce (shfl 4..32) gives half-k sums; khalf pair
// exchanges svU/S through LDS (Pl reused) once per routing iteration.
// ---------------------------------------------------------------------------
__global__ __launch_bounds__(512, 3)
void caps_main(const float4* __restrict__ T4, const float4* __restrict__ W4,
               float* __restrict__ out) {
    __shared__ float4 Pl[4 * 9 * 64];   // 36,864 B; reused as exchange buf
    const int tid = threadIdx.x;
    const int o = blockIdx.y;
    const int nbase = blockIdx.x * 4;
    const int cg = tid & 3;
    const int lane = tid & 63;
    const int kgp = lane >> 2;          // [0,16)
    const int wv = tid >> 6;            // [0,8)
    const int nl = wv >> 1;             // n_local in [0,4)
    const int khf = wv & 1;             // k-half: slabs [9*khf, 9*khf+9)

    // ---- phase 1, chunk 0: slabs g in [0,9), all 8 waves ----
    do_j(T4, W4, Pl, o, nbase, kgp + 16 * wv, cg, wv, lane);
    if (wv == 0)
        do_j(T4, W4, Pl, o, nbase, kgp + 16 * 8, cg, 8, lane);
    __syncthreads();

    float4 P[9];
    if (khf == 0) {
        #pragma unroll
        for (int jj = 0; jj < 9; ++jj)
            P[jj] = Pl[nl * 576 + jj * 64 + lane];
    }
    __syncthreads();

    // ---- phase 1, chunk 1: slabs g in [9,18), khalf1 waves only ----
    if (khf == 1) {
        const int m = wv >> 1;
        do_j(T4, W4, Pl, o, nbase, kgp + 16 * (9 + m),  cg, m,     lane);
        do_j(T4, W4, Pl, o, nbase, kgp + 16 * (13 + m), cg, 4 + m, lane);
        if (m == 0)
            do_j(T4, W4, Pl, o, nbase, kgp + 16 * 17, cg, 8, lane);
    }
    __syncthreads();
    if (khf == 1) {
        #pragma unroll
        for (int jj = 0; jj < 9; ++jj)
            P[jj] = Pl[nl * 576 + jj * 64 + lane];
    }
    __syncthreads();   // all P reads done before Pl is reused below

    // exchange region carved out of Pl: svU f4 at [wv][lane], S after it
    float4* xb4 = Pl;                       // 8*64 f4 = 8 KB
    float*  xbS = (float*)(Pl + 512);       // 8*64 f  = 2 KB

    // ---- phase 2: dynamic routing; wave owns half the k-range of its n ----
    float lj[9];
    #pragma unroll
    for (int jj = 0; jj < 9; ++jj) lj[jj] = 0.f;
    float4 vq = make_float4(0.f, 0.f, 0.f, 0.f);

    #pragma unroll
    for (int it = 0; it < 3; ++it) {
        float4 svU = make_float4(0.f, 0.f, 0.f, 0.f);
        float S;
        if (it == 0) {
            #pragma unroll
            for (int jj = 0; jj < 9; ++jj) add4(svU, P[jj]);
            #pragma unroll
            for (int m = 4; m < 64; m <<= 1)
                { const float4 t = shfl_xor4(svU, m); add4(svU, t); }
            S = 288.0f;
        } else {
            S = 0.f;
            #pragma unroll
            for (int jj = 0; jj < 9; ++jj) {
                const float e = __expf(lj[jj]);   // |lj| small; no max needed
                S += e;
                fma4(svU, e, P[jj]);
            }
            #pragma unroll
            for (int m = 4; m < 64; m <<= 1) {
                const float4 t = shfl_xor4(svU, m);
                add4(svU, t);
                S += __shfl_xor(S, m);
            }
        }
        // cross-wave (k-half pair) combine via LDS
        xb4[wv * 64 + lane] = svU;
        if (it) xbS[wv * 64 + lane] = S;
        __syncthreads();
        add4(svU, xb4[(wv ^ 1) * 64 + lane]);
        if (it) S += xbS[(wv ^ 1) * 64 + lane];
        if (it < 2) __syncthreads();   // buffer safe before next it's write

        const float invS = __frcp_rn(S);
        float4 s;
        s.x = svU.x * invS; s.y = svU.y * invS;
        s.z = svU.z * invS; s.w = svU.w * invS;
        float sq = s.x * s.x + s.y * s.y + s.z * s.z + s.w * s.w;
        sq += __shfl_xor(sq, 1);
        sq += __shfl_xor(sq, 2);
        const float scale = __fsqrt_rn(sq) / (1.0f + sq);
        vq.x = s.x * scale; vq.y = s.y * scale;
        vq.z = s.z * scale; vq.w = s.w * scale;

        if (it < 2) {
            #pragma unroll
            for (int jj = 0; jj < 9; ++jj) {
                float d = P[jj].x * vq.x + P[jj].y * vq.y +
                          P[jj].z * vq.z + P[jj].w * vq.w;
                d += __shfl_xor(d, 1);
                d += __shfl_xor(d, 2);
                lj[jj] += d;
            }
        }
    }

    // ---- store: khalf0 waves, lanes kgp==0 write their c-quad ----
    if (khf == 0 && kgp == 0) {
        const int n = nbase + nl;
        const int b = n / NSP;
        const int rm = n - b * NSP;
        float* op = out + (size_t)(b * 512 + o * 16 + cg * 4) * NSP + rm;
        op[0 * NSP] = vq.x;
        op[1 * NSP] = vq.y;
        op[2 * NSP] = vq.z;
        op[3 * NSP] = vq.w;
    }
}

extern "C" void kernel_launch(void* const* d_in, const int* in_sizes, int n_in,
                              void* d_out, int out_size, void* d_ws, size_t ws_size,
                              hipStream_t stream) {
    const float* x  = (const float*)d_in[0];   // (4, 256, 14, 14)
    const float* wt = (const float*)d_in[1];   // (32, 288, 8, 16)
    float* out = (float*)d_out;                // (4, 512, 12, 12)
    float4* T4 = (float4*)d_ws;                // 576*2304 floats = 5.3 MB

    build_T<<<dim3(576 * 576 / 256), 256, 0, stream>>>(x, T4);
    caps_main<<<dim3(144, 32), 512, 0, stream>>>(T4, (const float4*)wt, out);
}

// Round 6
// 124.860 us; speedup vs baseline: 1.4935x; 1.4935x over previous
//
#include <hip/hip_runtime.h>

static constexpr int OHW = 12, NSP = 144;

// ---------------------------------------------------------------------------
// build_T: gather x (4,256,14,14) -> T[n][k][i], n = b*144+oh*12+ow,
// k = (kh*3+kw)*32 + ic, i in [0,8). One float4 (4 consecutive i) per thread.
// (~4 us; fusing it into caps_main was tried in R1 and regressed by 11 us.)
// ---------------------------------------------------------------------------
__global__ void build_T(const float* __restrict__ x, float4* __restrict__ T4) {
    const int g = blockIdx.x * 256 + threadIdx.x;   // [0, 576*576)
    const int n = g / 576;                          // 576 float4 per n
    const int q = g - n * 576;
    const int r = q << 2;                           // float offset in row
    const int k = r >> 3;
    const int i0 = r & 7;                           // 0 or 4
    const int ic = k & 31;
    const int kk = k >> 5;
    const int kh = kk / 3, kw = kk - kh * 3;
    const int b = n / NSP;
    const int rm = n - b * NSP;
    const int oh = rm / OHW, ow = rm - oh * OHW;
    const float* xp = x + (size_t)(b * 256 + ic * 8 + i0) * 196
                        + (oh + kh) * 14 + (ow + kw);
    float4 v;
    v.x = xp[0];
    v.y = xp[196];
    v.z = xp[392];
    v.w = xp[588];
    T4[g] = v;
}

__device__ __forceinline__ void fma4(float4& a, float s, const float4& w) {
    a.x = fmaf(s, w.x, a.x);
    a.y = fmaf(s, w.y, a.y);
    a.z = fmaf(s, w.z, a.z);
    a.w = fmaf(s, w.w, a.w);
}

__device__ __forceinline__ float4 shfl_xor4(const float4& v, int m) {
    float4 r;
    r.x = __shfl_xor(v.x, m);
    r.y = __shfl_xor(v.y, m);
    r.z = __shfl_xor(v.z, m);
    r.w = __shfl_xor(v.w, m);
    return r;
}

__device__ __forceinline__ void loadw(float4 w[8], const float4* __restrict__ W4,
                                      int o, int k, int cg) {
    const float4* wp = W4 + (size_t)(o * 288 + k) * 32 + cg;
    #pragma unroll
    for (int i = 0; i < 8; ++i) w[i] = wp[i * 4];
}

// One k-slab (16 k x 4 c x 4 n) with weights already in registers.
// LDS write address = const + lane (lane-consecutive, conflict-free b128).
__device__ __forceinline__ void compute_slab(const float4* __restrict__ T4,
                                             const float4 w[8],
                                             float4* __restrict__ Pl,
                                             int nbase, int k, int g_local,
                                             int lane) {
    #pragma unroll
    for (int nn = 0; nn < 4; ++nn) {
        const float4* tp = T4 + (size_t)(nbase + nn) * 576 + k * 2;
        const float4 t0 = tp[0];
        const float4 t1 = tp[1];
        float4 a = make_float4(0.f, 0.f, 0.f, 0.f);
        fma4(a, t0.x, w[0]); fma4(a, t0.y, w[1]);
        fma4(a, t0.z, w[2]); fma4(a, t0.w, w[3]);
        fma4(a, t1.x, w[4]); fma4(a, t1.y, w[5]);
        fma4(a, t1.z, w[6]); fma4(a, t1.w, w[7]);
        Pl[nn * 576 + g_local * 64 + lane] = a;
    }
}

// ---------------------------------------------------------------------------
// caps_main: R0 structure (best measured: 73 us). Block = (o, 4 n's),
// 256 threads = 4 waves, wave = n in phase 2, P[18] f4 per lane (-> ~128
// regs/wave incl. AGPR-held P -> 16 waves/CU; R2-R5 showed every attempt to
// shrink this state made things worse: launch-bounds caps spill to scratch,
// 512-thread khalf split loses to barrier/imbalance overhead).
// This round's change: phase 1's branchy for(j){if(..) do_j} is replaced by
// an explicit per-wave static slab schedule with DOUBLE-BUFFERED weight
// registers (wA/wB issued up front, 3rd slab's w prefetched under the 1st
// slab's compute), so weight-load latency hides under the 128 FMAs/slab.
// Per-wave slabs: chunk0 wv0:{0,4,8} wv1:{1,5} wv2:{2,6} wv3:{3,7};
// chunk1 wv0:{12,16} wv1:{9,13,17} wv2:{10,14} wv3:{11,15}. Branches are
// wave-uniform. Math per P element identical to R0.
// Phase 2: wave = one n, lane = (cg, kgp), k = kgp + 16*jj; routing fully
// intra-wave: k-reduce = shfl_xor {4,8,16,32}, c-reduce = shfl_xor {1,2}.
// ---------------------------------------------------------------------------
__global__ __launch_bounds__(256, 4)
void caps_main(const float4* __restrict__ T4, const float4* __restrict__ W4,
               float* __restrict__ out) {
    __shared__ float4 Pl[4 * 9 * 64];   // 36,864 B
    const int tid = threadIdx.x;
    const int o = blockIdx.y;
    const int nbase = blockIdx.x * 4;
    const int cg = tid & 3;
    const int wv = tid >> 6;            // [0,4)
    const int lane = tid & 63;
    const int kgp = lane >> 2;          // [0,16)

    float4 P[18];
    float4 wA[8], wB[8];

    // ---- phase 1, chunk 0: slabs g in [0,9) ----
    loadw(wA, W4, o, kgp + 16 * wv, cg);
    loadw(wB, W4, o, kgp + 16 * (wv + 4), cg);
    if (wv == 0) {
        compute_slab(T4, wA, Pl, nbase, kgp, 0, lane);
        loadw(wA, W4, o, kgp + 16 * 8, cg);
        compute_slab(T4, wB, Pl, nbase, kgp + 16 * 4, 4, lane);
        compute_slab(T4, wA, Pl, nbase, kgp + 16 * 8, 8, lane);
    } else {
        compute_slab(T4, wA, Pl, nbase, kgp + 16 * wv, wv, lane);
        compute_slab(T4, wB, Pl, nbase, kgp + 16 * (wv + 4), wv + 4, lane);
    }
    __syncthreads();
    #pragma unroll
    for (int jj = 0; jj < 9; ++jj)
        P[jj] = Pl[wv * 576 + jj * 64 + lane];
    __syncthreads();

    // ---- phase 1, chunk 1: slabs g in [9,18), g_local = g - 9 ----
    const int h0 = (wv == 0) ? 12 : (8 + wv);   // wv: 12,9,10,11
    loadw(wA, W4, o, kgp + 16 * h0, cg);
    loadw(wB, W4, o, kgp + 16 * (h0 + 4), cg);
    if (wv == 1) {
        compute_slab(T4, wA, Pl, nbase, kgp + 16 * 9, 0, lane);
        loadw(wA, W4, o, kgp + 16 * 17, cg);
        compute_slab(T4, wB, Pl, nbase, kgp + 16 * 13, 4, lane);
        compute_slab(T4, wA, Pl, nbase, kgp + 16 * 17, 8, lane);
    } else {
        compute_slab(T4, wA, Pl, nbase, kgp + 16 * h0, h0 - 9, lane);
        compute_slab(T4, wB, Pl, nbase, kgp + 16 * (h0 + 4), h0 - 5, lane);
    }
    __syncthreads();
    #pragma unroll
    for (int jj = 9; jj < 18; ++jj)
        P[jj] = Pl[wv * 576 + (jj - 9) * 64 + lane];

    // ---- phase 2: dynamic routing, wave = n (= nbase + wv) ----
    float lj[18];
    #pragma unroll
    for (int jj = 0; jj < 18; ++jj) lj[jj] = 0.f;
    float4 vq = make_float4(0.f, 0.f, 0.f, 0.f);

    #pragma unroll
    for (int it = 0; it < 3; ++it) {
        float4 svU = make_float4(0.f, 0.f, 0.f, 0.f);
        float S;
        if (it == 0) {
            #pragma unroll
            for (int jj = 0; jj < 18; ++jj) {
                svU.x += P[jj].x; svU.y += P[jj].y;
                svU.z += P[jj].z; svU.w += P[jj].w;
            }
            #pragma unroll
            for (int m = 4; m < 64; m <<= 1) {
                const float4 t = shfl_xor4(svU, m);
                svU.x += t.x; svU.y += t.y; svU.z += t.z; svU.w += t.w;
            }
            S = 288.0f;
        } else {
            S = 0.f;
            #pragma unroll
            for (int jj = 0; jj < 18; ++jj) {
                const float e = __expf(lj[jj]);   // |lj| small; no max needed
                S += e;
                fma4(svU, e, P[jj]);
            }
            #pragma unroll
            for (int m = 4; m < 64; m <<= 1) {
                const float4 t = shfl_xor4(svU, m);
                svU.x += t.x; svU.y += t.y; svU.z += t.z; svU.w += t.w;
                S += __shfl_xor(S, m);
            }
        }
        const float invS = __frcp_rn(S);
        float4 s;
        s.x = svU.x * invS; s.y = svU.y * invS;
        s.z = svU.z * invS; s.w = svU.w * invS;
        float sq = s.x * s.x + s.y * s.y + s.z * s.z + s.w * s.w;
        sq += __shfl_xor(sq, 1);
        sq += __shfl_xor(sq, 2);
        const float scale = __fsqrt_rn(sq) / (1.0f + sq);
        vq.x = s.x * scale; vq.y = s.y * scale;
        vq.z = s.z * scale; vq.w = s.w * scale;

        if (it < 2) {
            #pragma unroll
            for (int jj = 0; jj < 18; ++jj) {
                float d = P[jj].x * vq.x + P[jj].y * vq.y +
                          P[jj].z * vq.z + P[jj].w * vq.w;
                d += __shfl_xor(d, 1);
                d += __shfl_xor(d, 2);
                lj[jj] += d;
            }
        }
    }

    // ---- store: lanes kgp==0 write their c-quad ----
    if ((lane >> 2) == 0) {
        const int n = nbase + wv;
        const int b = n / NSP;
        const int rm = n - b * NSP;
        float* op = out + (size_t)(b * 512 + o * 16 + cg * 4) * NSP + rm;
        op[0 * NSP] = vq.x;
        op[1 * NSP] = vq.y;
        op[2 * NSP] = vq.z;
        op[3 * NSP] = vq.w;
    }
}

extern "C" void kernel_launch(void* const* d_in, const int* in_sizes, int n_in,
                              void* d_out, int out_size, void* d_ws, size_t ws_size,
                              hipStream_t stream) {
    const float* x  = (const float*)d_in[0];   // (4, 256, 14, 14)
    const float* wt = (const float*)d_in[1];   // (32, 288, 8, 16)
    float* out = (float*)d_out;                // (4, 512, 12, 12)
    float4* T4 = (float4*)d_ws;                // 576*2304 floats = 5.3 MB

    build_T<<<dim3(576 * 576 / 256), 256, 0, stream>>>(x, T4);
    caps_main<<<dim3(144, 32), 256, 0, stream>>>(T4, (const float4*)wt, out);
}

// Round 7
// 120.771 us; speedup vs baseline: 1.5440x; 1.0339x over previous
//
#include <hip/hip_runtime.h>

static constexpr int OHW = 12, NSP = 144;

// ---------------------------------------------------------------------------
// build_T: gather x (4,256,14,14) -> T[n][k][i], n = b*144+oh*12+ow,
// k = (kh*3+kw)*32 + ic, i in [0,8). One float4 (4 consecutive i) per thread.
// (~4 us; fusing it into caps_main was tried in R1 and regressed by 11 us.)
// ---------------------------------------------------------------------------
__global__ void build_T(const float* __restrict__ x, float4* __restrict__ T4) {
    const int g = blockIdx.x * 256 + threadIdx.x;   // [0, 576*576)
    const int n = g / 576;                          // 576 float4 per n
    const int q = g - n * 576;
    const int r = q << 2;                           // float offset in row
    const int k = r >> 3;
    const int i0 = r & 7;                           // 0 or 4
    const int ic = k & 31;
    const int kk = k >> 5;
    const int kh = kk / 3, kw = kk - kh * 3;
    const int b = n / NSP;
    const int rm = n - b * NSP;
    const int oh = rm / OHW, ow = rm - oh * OHW;
    const float* xp = x + (size_t)(b * 256 + ic * 8 + i0) * 196
                        + (oh + kh) * 14 + (ow + kw);
    float4 v;
    v.x = xp[0];
    v.y = xp[196];
    v.z = xp[392];
    v.w = xp[588];
    T4[g] = v;
}

__device__ __forceinline__ void fma4(float4& a, float s, const float4& w) {
    a.x = fmaf(s, w.x, a.x);
    a.y = fmaf(s, w.y, a.y);
    a.z = fmaf(s, w.z, a.z);
    a.w = fmaf(s, w.w, a.w);
}

// ---- VALU-pipe shuffle/reduce helpers (phase 2) ---------------------------
// __shfl_xor lowers to ds_bpermute (LDS pipe, ~30-40 cyc chains). Phase 2's
// reduce trees were ~58 LDS-pipe ops per wave per routing iteration in serial
// chains -> the main VALU-idle source (R6 showed loads are not it). Replace:
//   xor1/xor2  -> DPP quad_perm (0xB1 / 0x4E)       [VALU]
//   kgp-reduce -> DPP row_ror:4 + row_ror:8 (rotate-reduce of the 4 stride-4
//                 values within each 16-lane row)    [VALU]
//                 + ds_swizzle 0x401F (xor16)        [LDS, 1 op]
//                 + __shfl_xor(.,32)                 [LDS, 1 op]
// Sum order changes (rotate vs xor association) -> ~1e-7 rel perturbation.
template <int CTRL>
__device__ __forceinline__ float dppmov(float v) {
    return __int_as_float(__builtin_amdgcn_update_dpp(
        0, __float_as_int(v), CTRL, 0xF, 0xF, true));
}

__device__ __forceinline__ float cred(float v) {       // sum over quad (xor1,2)
    v += dppmov<0xB1>(v);   // quad_perm [1,0,3,2]
    v += dppmov<0x4E>(v);   // quad_perm [2,3,0,1]
    return v;
}

__device__ __forceinline__ float kred(float v) {       // sum over 16 kgp (stride 4)
    v += dppmov<0x124>(v);  // row_ror:4
    v += dppmov<0x128>(v);  // row_ror:8  -> row-local stride-4 sum
    v += __int_as_float(__builtin_amdgcn_ds_swizzle(__float_as_int(v), 0x401F));
    v += __shfl_xor(v, 32);
    return v;
}

__device__ __forceinline__ void kred4(float4& v) {
    v.x = kred(v.x); v.y = kred(v.y); v.z = kred(v.z); v.w = kred(v.w);
}

__device__ __forceinline__ void loadw(float4 w[8], const float4* __restrict__ W4,
                                      int o, int k, int cg) {
    const float4* wp = W4 + (size_t)(o * 288 + k) * 32 + cg;
    #pragma unroll
    for (int i = 0; i < 8; ++i) w[i] = wp[i * 4];
}

// One k-slab (16 k x 4 c x 4 n) with weights already in registers.
// LDS write address = const + lane (lane-consecutive, conflict-free b128).
__device__ __forceinline__ void compute_slab(const float4* __restrict__ T4,
                                             const float4 w[8],
                                             float4* __restrict__ Pl,
                                             int nbase, int k, int g_local,
                                             int lane) {
    #pragma unroll
    for (int nn = 0; nn < 4; ++nn) {
        const float4* tp = T4 + (size_t)(nbase + nn) * 576 + k * 2;
        const float4 t0 = tp[0];
        const float4 t1 = tp[1];
        float4 a = make_float4(0.f, 0.f, 0.f, 0.f);
        fma4(a, t0.x, w[0]); fma4(a, t0.y, w[1]);
        fma4(a, t0.z, w[2]); fma4(a, t0.w, w[3]);
        fma4(a, t1.x, w[4]); fma4(a, t1.y, w[5]);
        fma4(a, t1.z, w[6]); fma4(a, t1.w, w[7]);
        Pl[nn * 576 + g_local * 64 + lane] = a;
    }
}

// ---------------------------------------------------------------------------
// caps_main: R0/R6 structure (best measured: 72.4 us). Block = (o, 4 n's),
// 256 threads = 4 waves, wave = n in phase 2, P[18] f4 per lane (~128
// regs/wave incl AGPR-held P -> 16 waves/CU; R2-R5 showed shrinking this
// state always loses: launch-bound caps spill, khalf split adds barriers).
// Phase 1: explicit per-wave static slab schedule, double-buffered weight
// regs (R6; neutral vs R0 but kept). Phase 2: this round's change -- all
// reduction shuffles moved from ds_bpermute (LDS pipe) to DPP/swizzle (see
// helpers above).
// ---------------------------------------------------------------------------
__global__ __launch_bounds__(256, 4)
void caps_main(const float4* __restrict__ T4, const float4* __restrict__ W4,
               float* __restrict__ out) {
    __shared__ float4 Pl[4 * 9 * 64];   // 36,864 B
    const int tid = threadIdx.x;
    const int o = blockIdx.y;
    const int nbase = blockIdx.x * 4;
    const int cg = tid & 3;
    const int wv = tid >> 6;            // [0,4)
    const int lane = tid & 63;
    const int kgp = lane >> 2;          // [0,16)

    float4 P[18];
    float4 wA[8], wB[8];

    // ---- phase 1, chunk 0: slabs g in [0,9) ----
    loadw(wA, W4, o, kgp + 16 * wv, cg);
    loadw(wB, W4, o, kgp + 16 * (wv + 4), cg);
    if (wv == 0) {
        compute_slab(T4, wA, Pl, nbase, kgp, 0, lane);
        loadw(wA, W4, o, kgp + 16 * 8, cg);
        compute_slab(T4, wB, Pl, nbase, kgp + 16 * 4, 4, lane);
        compute_slab(T4, wA, Pl, nbase, kgp + 16 * 8, 8, lane);
    } else {
        compute_slab(T4, wA, Pl, nbase, kgp + 16 * wv, wv, lane);
        compute_slab(T4, wB, Pl, nbase, kgp + 16 * (wv + 4), wv + 4, lane);
    }
    __syncthreads();
    #pragma unroll
    for (int jj = 0; jj < 9; ++jj)
        P[jj] = Pl[wv * 576 + jj * 64 + lane];
    __syncthreads();

    // ---- phase 1, chunk 1: slabs g in [9,18), g_local = g - 9 ----
    const int h0 = (wv == 0) ? 12 : (8 + wv);   // wv: 12,9,10,11
    loadw(wA, W4, o, kgp + 16 * h0, cg);
    loadw(wB, W4, o, kgp + 16 * (h0 + 4), cg);
    if (wv == 1) {
        compute_slab(T4, wA, Pl, nbase, kgp + 16 * 9, 0, lane);
        loadw(wA, W4, o, kgp + 16 * 17, cg);
        compute_slab(T4, wB, Pl, nbase, kgp + 16 * 13, 4, lane);
        compute_slab(T4, wA, Pl, nbase, kgp + 16 * 17, 8, lane);
    } else {
        compute_slab(T4, wA, Pl, nbase, kgp + 16 * h0, h0 - 9, lane);
        compute_slab(T4, wB, Pl, nbase, kgp + 16 * (h0 + 4), h0 - 5, lane);
    }
    __syncthreads();
    #pragma unroll
    for (int jj = 9; jj < 18; ++jj)
        P[jj] = Pl[wv * 576 + (jj - 9) * 64 + lane];

    // ---- phase 2: dynamic routing, wave = n (= nbase + wv) ----
    float lj[18];
    #pragma unroll
    for (int jj = 0; jj < 18; ++jj) lj[jj] = 0.f;
    float4 vq = make_float4(0.f, 0.f, 0.f, 0.f);

    #pragma unroll
    for (int it = 0; it < 3; ++it) {
        float4 svU = make_float4(0.f, 0.f, 0.f, 0.f);
        float S;
        if (it == 0) {
            #pragma unroll
            for (int jj = 0; jj < 18; ++jj) {
                svU.x += P[jj].x; svU.y += P[jj].y;
                svU.z += P[jj].z; svU.w += P[jj].w;
            }
            kred4(svU);
            S = 288.0f;
        } else {
            S = 0.f;
            #pragma unroll
            for (int jj = 0; jj < 18; ++jj) {
                const float e = __expf(lj[jj]);   // |lj| small; no max needed
                S += e;
                fma4(svU, e, P[jj]);
            }
            kred4(svU);
            S = kred(S);
        }
        const float invS = __frcp_rn(S);
        float4 s;
        s.x = svU.x * invS; s.y = svU.y * invS;
        s.z = svU.z * invS; s.w = svU.w * invS;
        float sq = s.x * s.x + s.y * s.y + s.z * s.z + s.w * s.w;
        sq = cred(sq);
        const float scale = __fsqrt_rn(sq) / (1.0f + sq);
        vq.x = s.x * scale; vq.y = s.y * scale;
        vq.z = s.z * scale; vq.w = s.w * scale;

        if (it < 2) {
            #pragma unroll
            for (int jj = 0; jj < 18; ++jj) {
                float d = P[jj].x * vq.x + P[jj].y * vq.y +
                          P[jj].z * vq.z + P[jj].w * vq.w;
                lj[jj] += cred(d);
            }
        }
    }

    // ---- store: lanes kgp==0 write their c-quad ----
    if ((lane >> 2) == 0) {
        const int n = nbase + wv;
        const int b = n / NSP;
        const int rm = n - b * NSP;
        float* op = out + (size_t)(b * 512 + o * 16 + cg * 4) * NSP + rm;
        op[0 * NSP] = vq.x;
        op[1 * NSP] = vq.y;
        op[2 * NSP] = vq.z;
        op[3 * NSP] = vq.w;
    }
}

extern "C" void kernel_launch(void* const* d_in, const int* in_sizes, int n_in,
                              void* d_out, int out_size, void* d_ws, size_t ws_size,
                              hipStream_t stream) {
    const float* x  = (const float*)d_in[0];   // (4, 256, 14, 14)
    const float* wt = (const float*)d_in[1];   // (32, 288, 8, 16)
    float* out = (float*)d_out;                // (4, 512, 12, 12)
    float4* T4 = (float4*)d_ws;                // 576*2304 floats = 5.3 MB

    build_T<<<dim3(576 * 576 / 256), 256, 0, stream>>>(x, T4);
    caps_main<<<dim3(144, 32), 256, 0, stream>>>(T4, (const float4*)wt, out);
}